// Round 1
// baseline (14192.168 us; speedup 1.0000x reference)
//
#include <hip/hip_runtime.h>
#include <stdint.h>
#include <math.h>

// Set to 0 if validation shows wholesale sample mismatch (legacy JAX threefry counters)
#define JAX_PARTITIONABLE 1

#define B_ 512
#define SEQ_ 50
#define H_ 256
#define H2_ 128
#define T_ 60
#define S_ 6
#define EMB_ 16
#define NL_ 2
#define TG_ 768     // 3*H
#define CAT_ 4096   // G*G
#define GUMBEL_N 629145600u  // (S-1)*T*B*CAT
#define NOISE_N 7864320u     // T*B*H

// ---------------- Threefry-2x32 (20 rounds), matches jax._src.prng ----------------
__host__ __device__ inline void tf2x32(uint32_t k0, uint32_t k1, uint32_t x0, uint32_t x1,
                                       uint32_t& o0, uint32_t& o1) {
  uint32_t ks2 = k0 ^ k1 ^ 0x1BD11BDAu;
  x0 += k0; x1 += k1;
#define TFR(r) do { x0 += x1; x1 = (x1 << r) | (x1 >> (32 - r)); x1 ^= x0; } while (0)
  TFR(13); TFR(15); TFR(26); TFR(6);
  x0 += k1; x1 += ks2 + 1u;
  TFR(17); TFR(29); TFR(16); TFR(24);
  x0 += ks2; x1 += k0 + 2u;
  TFR(13); TFR(15); TFR(26); TFR(6);
  x0 += k0; x1 += k1 + 3u;
  TFR(17); TFR(29); TFR(16); TFR(24);
  x0 += k1; x1 += ks2 + 4u;
  TFR(13); TFR(15); TFR(26); TFR(6);
  x0 += ks2; x1 += k0 + 5u;
#undef TFR
  o0 = x0; o1 = x1;
}

__device__ inline uint32_t jax_bits(uint32_t k0, uint32_t k1, uint32_t i, uint32_t n) {
#if JAX_PARTITIONABLE
  (void)n;
  uint32_t a, b;
  tf2x32(k0, k1, 0u, i, a, b);   // 64-bit iota counter: hi=0, lo=i
  return a ^ b;
#else
  uint32_t half = n >> 1;
  uint32_t lo = (i < half) ? i : (i - half);
  uint32_t a, b;
  tf2x32(k0, k1, lo, lo + half, a, b);
  return (i < half) ? a : b;
#endif
}

__device__ inline float bits_to_f01(uint32_t bits) {
  // ((bits>>9) | 0x3f800000) bitcast - 1.0f  -> [0,1), exact ops
  return __uint_as_float((bits >> 9) | 0x3f800000u) - 1.0f;
}

// erf_inv, CHLO/Giles f32 polynomial; w from double log (~correctly rounded)
__device__ inline float erfinv_f(float x) {
  double xd = (double)x;
  float w = (float)(-log((1.0 - xd) * (1.0 + xd)));
  float p;
  if (w < 5.0f) {
    w = __fadd_rn(w, -2.5f);
    p = 2.81022636e-08f;
    p = __fadd_rn(3.43273939e-07f, __fmul_rn(p, w));
    p = __fadd_rn(-3.5233877e-06f, __fmul_rn(p, w));
    p = __fadd_rn(-4.39150654e-06f, __fmul_rn(p, w));
    p = __fadd_rn(0.00021858087f, __fmul_rn(p, w));
    p = __fadd_rn(-0.00125372503f, __fmul_rn(p, w));
    p = __fadd_rn(-0.00417768164f, __fmul_rn(p, w));
    p = __fadd_rn(0.246640727f, __fmul_rn(p, w));
    p = __fadd_rn(1.50140941f, __fmul_rn(p, w));
  } else {
    w = __fadd_rn(__fsqrt_rn(w), -3.0f);
    p = -0.000200214257f;
    p = __fadd_rn(0.000100950558f, __fmul_rn(p, w));
    p = __fadd_rn(0.00134934322f, __fmul_rn(p, w));
    p = __fadd_rn(-0.00367342844f, __fmul_rn(p, w));
    p = __fadd_rn(0.00573950773f, __fmul_rn(p, w));
    p = __fadd_rn(-0.0076224613f, __fmul_rn(p, w));
    p = __fadd_rn(0.00943887047f, __fmul_rn(p, w));
    p = __fadd_rn(1.00167406f, __fmul_rn(p, w));
    p = __fadd_rn(2.83297682f, __fmul_rn(p, w));
  }
  return __fmul_rn(p, x);
}

__device__ inline float gumbel_from_bits(uint32_t bits) {
  float f = bits_to_f01(bits);
  float u = (f > 0.0f) ? f : 1.17549435e-38f;  // minval = tiny
  float l1 = (float)log((double)u);            // < 0
  float l2 = (float)log((double)(-l1));
  return -l2;
}

// ---------------- init: etype/eidx, per-type grouping, x0 ----------------
// ip layout (ints): [0..511] etype, [512..1023] eidx, [1024..1535] order,
//   tbl = ip+1536: tbl[0]=nrt, tbl[1..36]=rt_type, tbl[37..72]=rt_start, tbl[73..108]=rt_rows
__global__ __launch_bounds__(512) void k_init(const float* __restrict__ hist,
                                              float* __restrict__ x0buf, int* __restrict__ ip) {
  int b = threadIdx.x;
  if (b < B_) {
    float tv = hist[b * 4800 + 5];          // history[b][0][0][5]
    int et = (int)tv;
    et = et < 0 ? 0 : (et > 9 ? 9 : et);
    const int mp[10] = {0, 1, 4, 2, 3, 4, 4, 4, 4, 4};
    ip[b] = et;
    ip[512 + b] = mp[et];
    x0buf[b * 2 + 0] = hist[b * 4800 + 49 * 6 + 0];
    x0buf[b * 2 + 1] = hist[b * 4800 + 49 * 6 + 1];
  }
  __syncthreads();
  if (b == 0) {
    int cnt[5] = {0, 0, 0, 0, 0};
    for (int i = 0; i < B_; i++) cnt[ip[512 + i]]++;
    int off[6];
    off[0] = 0;
    for (int e = 0; e < 5; e++) off[e + 1] = off[e] + cnt[e];
    int pos[5];
    for (int e = 0; e < 5; e++) pos[e] = off[e];
    for (int i = 0; i < B_; i++) { int e = ip[512 + i]; ip[1024 + pos[e]++] = i; }
    int* tbl = ip + 1536;
    int nrt = 0;
    for (int e = 0; e < 5; e++) {
      int n = cnt[e];
      for (int s = 0; s < n; s += 16) {
        tbl[1 + nrt] = e;
        tbl[37 + nrt] = off[e] + s;
        tbl[73 + nrt] = (n - s) < 16 ? (n - s) : 16;
        nrt++;
      }
    }
    tbl[0] = nrt;
  }
}

__global__ void k_zero(uint32_t* p, int n) {
  int i = blockIdx.x * blockDim.x + threadIdx.x;
  if (i < n) p[i] = 0u;
}

// ---------------- feature extractor: relu(x@W1+b1)@W2+b2, x = [ego(6) | emb(16)] ----------------
__global__ __launch_bounds__(256) void k_feat(const float* __restrict__ hist, const float* __restrict__ emb,
    const float* __restrict__ W1, const float* __restrict__ b1,
    const float* __restrict__ W2, const float* __restrict__ b2,
    const int* __restrict__ ip, float* __restrict__ featbuf) {
  __shared__ float xs[16][22];
  __shared__ float t1[16][H_];
  int row0 = blockIdx.x * 16;
  int tid = threadIdx.x;
  for (int idx = tid; idx < 16 * 22; idx += 256) {
    int r = idx / 22, c = idx % 22;
    int g = row0 + r;
    int b = g / SEQ_, s = g % SEQ_;
    xs[r][c] = (c < 6) ? hist[b * 4800 + s * 6 + c] : emb[ip[b] * EMB_ + (c - 6)];
  }
  __syncthreads();
  int j = tid;
  float t1l[16];
  for (int r = 0; r < 16; r++) {
    double acc = 0.0;
    for (int k = 0; k < 22; k++) acc += (double)xs[r][k] * (double)W1[k * H_ + j];
    t1l[r] = fmaxf((float)(acc + (double)b1[j]), 0.0f);
  }
  for (int r = 0; r < 16; r++) t1[r][j] = t1l[r];
  __syncthreads();
  for (int r = 0; r < 16; r++) {
    double acc = 0.0;
    for (int k = 0; k < H_; k++) acc += (double)t1[r][k] * (double)W2[k * H_ + j];
    float v = (float)(acc + (double)b2[j]);
    int g = row0 + r;
    int b = g / SEQ_, s = g % SEQ_;
    featbuf[(size_t)s * (B_ * H_) + (size_t)b * H_ + j] = v;  // [t][b][h]
  }
}

// ---------------- generic GRU step ----------------
// GROUPED: per-type weights enc_W[e][layer]; rows via order[]. Else rows = bx*16 + r, weights direct.
template <int D1, bool GROUPED>
__global__ __launch_bounds__(256) void k_gru(
    const float* __restrict__ x, const float* __restrict__ hin,
    float* __restrict__ hout, float* __restrict__ ys,
    const float* __restrict__ Wih_base, const float* __restrict__ Whh_base,
    const float* __restrict__ bih_base, const float* __restrict__ bhh_base,
    int layer, const int* __restrict__ ip) {
  __shared__ float xs[16][(D1 == 2) ? 2 : H_];
  __shared__ float hs[16][H_];
  __shared__ int rowb[16];
  int bx = blockIdx.x, by = blockIdx.y;
  const int* tbl = ip + 1536;
  const int* order = ip + 1024;
  int e = 0, start, nr;
  if (GROUPED) {
    int nrt = tbl[0];
    if (bx >= nrt) return;
    e = tbl[1 + bx];
    start = tbl[37 + bx];
    nr = tbl[73 + bx];
  } else {
    start = bx * 16;
    nr = 16;
  }
  int tid = threadIdx.x;
  for (int idx = tid; idx < 16 * H_; idx += 256) {
    int r = idx >> 8;
    int k = idx & 255;
    int rr = (r < nr) ? r : 0;
    int b = GROUPED ? order[start + rr] : (start + rr);
    if (k == 0) rowb[r] = b;
    hs[r][k] = hin[b * H_ + k];
    if (D1 == H_) xs[r][k] = x[b * H_ + k];
    else if (k < D1) xs[r][k] = x[b * D1 + k];
  }
  __syncthreads();
  size_t woff = (size_t)(GROUPED ? (e * NL_ + layer) : 0);
  const float* Wih = Wih_base + woff * (size_t)D1 * TG_;
  const float* Whh = Whh_base + woff * (size_t)H_ * TG_;
  const float* bih = bih_base + woff * TG_;
  const float* bhh = bhh_base + woff * TG_;
  int j = tid & 31, rs = tid >> 5;  // rs in 0..7; rows rs and rs+8
  int hc = by * 32 + j;
  int cr = hc, cz = H_ + hc, cn = 2 * H_ + hc;
  double ra0 = 0, ra1 = 0, za0 = 0, za1 = 0, ni0 = 0, ni1 = 0, nh0 = 0, nh1 = 0;
  for (int k = 0; k < H_; k++) {
    float wrh = Whh[k * TG_ + cr], wzh = Whh[k * TG_ + cz], wnh = Whh[k * TG_ + cn];
    float h0v = hs[rs][k], h1v = hs[rs + 8][k];
    ra0 += (double)h0v * wrh; ra1 += (double)h1v * wrh;
    za0 += (double)h0v * wzh; za1 += (double)h1v * wzh;
    nh0 += (double)h0v * wnh; nh1 += (double)h1v * wnh;
    if (D1 == H_) {
      float wri = Wih[k * TG_ + cr], wzi = Wih[k * TG_ + cz], wni = Wih[k * TG_ + cn];
      float x0v = xs[rs][k], x1v = xs[rs + 8][k];
      ra0 += (double)x0v * wri; ra1 += (double)x1v * wri;
      za0 += (double)x0v * wzi; za1 += (double)x1v * wzi;
      ni0 += (double)x0v * wni; ni1 += (double)x1v * wni;
    }
  }
  if (D1 != H_) {
    for (int k = 0; k < D1; k++) {
      float wri = Wih[k * TG_ + cr], wzi = Wih[k * TG_ + cz], wni = Wih[k * TG_ + cn];
      float x0v = xs[rs][k], x1v = xs[rs + 8][k];
      ra0 += (double)x0v * wri; ra1 += (double)x1v * wri;
      za0 += (double)x0v * wzi; za1 += (double)x1v * wzi;
      ni0 += (double)x0v * wni; ni1 += (double)x1v * wni;
    }
  }
  double br_i = (double)bih[cr], bz_i = (double)bih[cz], bn_i = (double)bih[cn];
  double br_h = (double)bhh[cr], bz_h = (double)bhh[cz], bn_h = (double)bhh[cn];
  for (int p = 0; p < 2; p++) {
    int r = rs + 8 * p;
    if (r >= nr) continue;
    double ra = p ? ra1 : ra0, za = p ? za1 : za0, ni = p ? ni1 : ni0, nh = p ? nh1 : nh0;
    double rr = 1.0 / (1.0 + exp(-(ra + br_i + br_h)));
    double zz = 1.0 / (1.0 + exp(-(za + bz_i + bz_h)));
    double nn = tanh((ni + bn_i) + rr * (nh + bn_h));
    double hv = (double)hs[r][hc];
    float hnew = (float)((1.0 - zz) * nn + zz * hv);
    int b = rowb[r];
    hout[b * H_ + hc] = hnew;
    if (ys) ys[b * H_ + hc] = hnew;
  }
}

// ---------------- heads: traj (-> out s=0), conf mean * decay (-> out tail) ----------------
__global__ __launch_bounds__(256) void k_heads(const float* __restrict__ lh,
    const float* __restrict__ hgW1, const float* __restrict__ hgb1,
    const float* __restrict__ hgW2, const float* __restrict__ hgb2,
    const float* __restrict__ hgW3, const float* __restrict__ hgb3,
    const float* __restrict__ ceW1, const float* __restrict__ ceb1,
    const float* __restrict__ ceW2, const float* __restrict__ ceb2,
    float* __restrict__ out) {
  __shared__ float hsm[16][H_];
  __shared__ float t1[16][H_];
  __shared__ float t2[16][H2_];
  __shared__ float c2s[16][T_];
  int row0 = blockIdx.x * 16;
  int tid = threadIdx.x;
  for (int idx = tid; idx < 16 * H_; idx += 256) {
    int r = idx >> 8, k = idx & 255;
    hsm[r][k] = lh[(size_t)(row0 + r) * H_ + k];
  }
  __syncthreads();
  {
    int j = tid;
    for (int r = 0; r < 16; r++) {
      double a = 0;
      for (int k = 0; k < H_; k++) a += (double)hsm[r][k] * (double)hgW1[k * H_ + j];
      t1[r][j] = fmaxf((float)(a + (double)hgb1[j]), 0.0f);
    }
  }
  __syncthreads();
  if (tid < H2_) {
    int j = tid;
    for (int r = 0; r < 16; r++) {
      double a = 0;
      for (int k = 0; k < H_; k++) a += (double)t1[r][k] * (double)hgW2[k * H2_ + j];
      t2[r][j] = fmaxf((float)(a + (double)hgb2[j]), 0.0f);
    }
  }
  __syncthreads();
  if (tid < 2 * T_) {
    int j = tid;
    for (int r = 0; r < 16; r++) {
      double a = 0;
      for (int k = 0; k < H2_; k++) a += (double)t2[r][k] * (double)hgW3[k * (2 * T_) + j];
      float v = (float)(a + (double)hgb3[j]);
      int b = row0 + r;
      int t = j >> 1, c = j & 1;
      out[(((size_t)b * S_ + 0) * T_ + t) * 2 + c] = v;
    }
  }
  __syncthreads();
  if (tid < H2_) {
    int j = tid;
    for (int r = 0; r < 16; r++) {
      double a = 0;
      for (int k = 0; k < H_; k++) a += (double)hsm[r][k] * (double)ceW1[k * H2_ + j];
      t2[r][j] = fmaxf((float)(a + (double)ceb1[j]), 0.0f);
    }
  }
  __syncthreads();
  if (tid < T_) {
    int j = tid;
    for (int r = 0; r < 16; r++) {
      double a = 0;
      for (int k = 0; k < H2_; k++) a += (double)t2[r][k] * (double)ceW2[k * T_ + j];
      c2s[r][j] = (float)(a + (double)ceb2[j]);
    }
  }
  __syncthreads();
  if (tid < 16) {
    int r = tid;
    int b = row0 + r;
    double s = 0;
    for (int j = 0; j < T_; j++) s += (double)c2s[r][j];
    float m = (float)(s / 60.0);
    for (int sd = 0; sd < S_; sd++) {
      float d = (float)pow((double)0.9f, (double)sd);
      out[368640 + b * S_ + sd] = __fmul_rn(m, d);
    }
  }
}

// ---------------- hp layer1: th = lh + noise*scale (threefry+erfinv on the fly), h1 = relu(th@W1+b1) ----------------
__global__ __launch_bounds__(256) void k_hp1(const float* __restrict__ lh,
    const float* __restrict__ W1, const float* __restrict__ b1,
    float* __restrict__ h1buf, uint32_t nk0, uint32_t nk1) {
  __shared__ float th[16][H_];
  int row0 = blockIdx.x * 16;
  int tid = threadIdx.x;
  const float SQRT2F = 1.4142135623730951f;
  const float LO = -0x1.fffffep-1f;  // nextafter(-1,0)
  for (int idx = tid; idx < 16 * H_; idx += 256) {
    int r = idx >> 8, k = idx & 255;
    int g = row0 + r;
    int t = g / B_, b = g % B_;
    uint32_t i = ((uint32_t)t * B_ + (uint32_t)b) * H_ + (uint32_t)k;
    uint32_t bits = jax_bits(nk0, nk1, i, NOISE_N);
    float f = bits_to_f01(bits);
    float u = fmaxf(LO, __fadd_rn(__fmul_rn(f, 2.0f), LO));
    float nz = __fmul_rn(SQRT2F, erfinv_f(u));
    float sc = __fdiv_rn(__fmul_rn(0.1f, (float)t), 60.0f);
    th[r][k] = __fadd_rn(lh[(size_t)b * H_ + k], __fmul_rn(nz, sc));
  }
  __syncthreads();
  int j = tid;
  double acc[16];
  for (int r = 0; r < 16; r++) acc[r] = 0.0;
  for (int k = 0; k < H_; k++) {
    double w = (double)W1[k * H_ + j];
    for (int r = 0; r < 16; r++) acc[r] += (double)th[r][k] * w;
  }
  double bb = (double)b1[j];
  for (int r = 0; r < 16; r++)
    h1buf[(size_t)(row0 + r) * H_ + j] = fmaxf((float)(acc[r] + bb), 0.0f);
}

// ---------------- hp layer2 + gumbel + argmax (fused) ----------------
__global__ __launch_bounds__(256) void k_hp2(const float* __restrict__ h1buf,
    const float* __restrict__ W2, const float* __restrict__ b2,
    unsigned long long* __restrict__ samples, uint32_t sk0, uint32_t sk1) {
  __shared__ float h1[16][H_];
  int row0 = blockIdx.x * 16;
  int cat0 = blockIdx.y * 128;
  int tid = threadIdx.x;
  for (int idx = tid; idx < 16 * H_; idx += 256) {
    int r = idx >> 8, k = idx & 255;
    h1[r][k] = h1buf[(size_t)(row0 + r) * H_ + k];
  }
  __syncthreads();
  int j = tid & 127;
  int half = tid >> 7;  // 0: rows 0..7, 1: rows 8..15
  int cat = cat0 + j;
  double acc[8];
  for (int r = 0; r < 8; r++) acc[r] = 0.0;
  for (int k = 0; k < H_; k++) {
    double w = (double)W2[(size_t)k * CAT_ + cat];
    for (int r = 0; r < 8; r++) acc[r] += (double)h1[half * 8 + r][k] * w;
  }
  float logit[8];
  double bb = (double)b2[cat];
  for (int r = 0; r < 8; r++) logit[r] = (float)(acc[r] + bb);
  int t = row0 / B_;        // uniform per block (512 % 16 == 0)
  int bbase = row0 % B_;
  for (int s = 0; s < S_ - 1; s++) {
    for (int r = 0; r < 8; r++) {
      int rr = half * 8 + r;
      int brow = bbase + rr;
      uint32_t i = (((uint32_t)s * T_ + (uint32_t)t) * B_ + (uint32_t)brow) * CAT_ + (uint32_t)cat;
      float gv = gumbel_from_bits(jax_bits(sk0, sk1, i, GUMBEL_N));
      float score = __fadd_rn(gv, logit[r]);
      uint32_t sb = __float_as_uint(score);
      sb = (sb & 0x80000000u) ? ~sb : (sb | 0x80000000u);
      unsigned long long p =
          (((unsigned long long)sb) << 32) | (unsigned long long)(~(uint32_t)cat);
      for (int off = 32; off > 0; off >>= 1) {
        unsigned long long q = __shfl_xor(p, off, 64);
        if (q > p) p = q;
      }
      if ((tid & 63) == 0)
        atomicMax(&samples[((size_t)s * T_ + t) * B_ + brow], p);
    }
  }
}

// ---------------- decode samples -> grid points ----------------
__global__ void k_emit(const unsigned long long* __restrict__ samples, float* __restrict__ out) {
  int gid = blockIdx.x * blockDim.x + threadIdx.x;
  if (gid >= (S_ - 1) * T_ * B_) return;
  int b = gid % B_;
  int t = (gid / B_) % T_;
  int s = gid / (B_ * T_);
  unsigned long long v = samples[gid];
  uint32_t cat = ~(uint32_t)(v & 0xFFFFFFFFu);
  float xi = (float)(cat & 63u);
  float yi = (float)(cat >> 6);
  float px = -50.0f + xi * 1.5625f + 0.78125f;  // exact f32 arithmetic
  float py = -50.0f + yi * 1.5625f + 0.78125f;
  size_t o = (((size_t)b * S_ + (size_t)(s + 1)) * T_ + t) * 2;
  out[o] = px;
  out[o + 1] = py;
}

// ---------------- host ----------------
extern "C" void kernel_launch(void* const* d_in, const int* in_sizes, int n_in,
                              void* d_out, int out_size, void* d_ws, size_t ws_size,
                              hipStream_t stream) {
  (void)in_sizes; (void)n_in; (void)out_size; (void)ws_size;
  const float* hist   = (const float*)d_in[0];
  const float* emb    = (const float*)d_in[1];
  const float* feW1   = (const float*)d_in[2];
  const float* feb1   = (const float*)d_in[3];
  const float* feW2   = (const float*)d_in[4];
  const float* feb2   = (const float*)d_in[5];
  const float* encWih = (const float*)d_in[6];
  const float* encWhh = (const float*)d_in[7];
  const float* encbih = (const float*)d_in[8];
  const float* encbhh = (const float*)d_in[9];
  const float* dWih0  = (const float*)d_in[10];
  const float* dWhh0  = (const float*)d_in[11];
  const float* dbih0  = (const float*)d_in[12];
  const float* dbhh0  = (const float*)d_in[13];
  const float* dWih1  = (const float*)d_in[14];
  const float* dWhh1  = (const float*)d_in[15];
  const float* dbih1  = (const float*)d_in[16];
  const float* dbhh1  = (const float*)d_in[17];
  const float* hgW1   = (const float*)d_in[18];
  const float* hgb1   = (const float*)d_in[19];
  const float* hgW2   = (const float*)d_in[20];
  const float* hgb2   = (const float*)d_in[21];
  const float* hgW3   = (const float*)d_in[22];
  const float* hgb3   = (const float*)d_in[23];
  const float* ceW1   = (const float*)d_in[24];
  const float* ceb1   = (const float*)d_in[25];
  const float* ceW2   = (const float*)d_in[26];
  const float* ceb2   = (const float*)d_in[27];
  const float* hpW1   = (const float*)d_in[28];
  const float* hpb1   = (const float*)d_in[29];
  const float* hpW2   = (const float*)d_in[30];
  const float* hpb2   = (const float*)d_in[31];
  float* out = (float*)d_out;
  float* ws = (float*)d_ws;

  // workspace layout (floats)
  float* feat  = ws;                       // 6,553,600  [t][b][h]
  float* ys0   = ws + 6553600;             // 6,553,600  [t][b][h]
  float* h1hp  = ws;                       // 7,864,320 (aliases feat+start of ys0; both dead by then)
  float* hA0   = ws + 13107200;
  float* hB0   = hA0 + 131072;
  float* hA1   = hB0 + 131072;
  float* hB1   = hA1 + 131072;
  float* dech0 = hB1 + 131072;
  float* lh    = dech0 + 131072;
  float* x0buf = lh + 131072;              // 1024
  int*   ip    = (int*)(x0buf + 1024);     // ~1645 ints used, 2048 reserved
  unsigned long long* samples =
      (unsigned long long*)(((uintptr_t)(ip + 2048) + 255) & ~(uintptr_t)255);

  // JAX PRNG keys: key(42) = (0,42); split -> k_noise, k_samp
  uint32_t kn0, kn1, ks0, ks1;
#if JAX_PARTITIONABLE
  tf2x32(0u, 42u, 0u, 0u, kn0, kn1);
  tf2x32(0u, 42u, 0u, 1u, ks0, ks1);
#else
  { uint32_t a0, a1, b0, b1;
    tf2x32(0u, 42u, 0u, 2u, a0, a1);
    tf2x32(0u, 42u, 1u, 3u, b0, b1);
    kn0 = a0; kn1 = b0; ks0 = a1; ks1 = b1; }
#endif

  k_init<<<dim3(1), dim3(512), 0, stream>>>(hist, x0buf, ip);
  k_zero<<<dim3((524288 + 255) / 256), dim3(256), 0, stream>>>((uint32_t*)hA0, 524288);
  k_zero<<<dim3((307200 + 255) / 256), dim3(256), 0, stream>>>((uint32_t*)samples, 307200);
  k_feat<<<dim3(1600), dim3(256), 0, stream>>>(hist, emb, feW1, feb1, feW2, feb2, ip, feat);

  // encoder layer 0 (writes ys0), then layer 1
  float* hin = hA0; float* hout = hB0;
  for (int t = 0; t < SEQ_; t++) {
    k_gru<H_, true><<<dim3(36, 8), dim3(256), 0, stream>>>(
        feat + (size_t)t * 131072, hin, hout, ys0 + (size_t)t * 131072,
        encWih, encWhh, encbih, encbhh, 0, ip);
    float* tmp = hin; hin = hout; hout = tmp;
  }
  float* ench0 = hin;
  float* hin1 = hA1; float* hout1 = hB1;
  for (int t = 0; t < SEQ_; t++) {
    k_gru<H_, true><<<dim3(36, 8), dim3(256), 0, stream>>>(
        ys0 + (size_t)t * 131072, hin1, hout1, nullptr,
        encWih, encWhh, encbih, encbhh, 1, ip);
    float* tmp = hin1; hin1 = hout1; hout1 = tmp;
  }
  float* ench1 = hin1;

  // decoder cells
  k_gru<2, false><<<dim3(32, 8), dim3(256), 0, stream>>>(
      x0buf, ench0, dech0, nullptr, dWih0, dWhh0, dbih0, dbhh0, 0, ip);
  k_gru<H_, false><<<dim3(32, 8), dim3(256), 0, stream>>>(
      dech0, ench1, lh, nullptr, dWih1, dWhh1, dbih1, dbhh1, 0, ip);

  k_heads<<<dim3(32), dim3(256), 0, stream>>>(lh, hgW1, hgb1, hgW2, hgb2, hgW3, hgb3,
                                              ceW1, ceb1, ceW2, ceb2, out);
  k_hp1<<<dim3(1920), dim3(256), 0, stream>>>(lh, hpW1, hpb1, h1hp, kn0, kn1);
  k_hp2<<<dim3(1920, 32), dim3(256), 0, stream>>>(h1hp, hpW2, hpb2, samples, ks0, ks1);
  k_emit<<<dim3(600), dim3(256), 0, stream>>>(samples, out);
}

// Round 2
// 9643.341 us; speedup vs baseline: 1.4717x; 1.4717x over previous
//
#include <hip/hip_runtime.h>
#include <stdint.h>
#include <math.h>

#define JAX_PARTITIONABLE 1

#define B_ 512
#define SEQ_ 50
#define H_ 256
#define H2_ 128
#define T_ 60
#define S_ 6
#define EMB_ 16
#define NL_ 2
#define TG_ 768     // 3*H
#define CAT_ 4096   // G*G
#define GUMBEL_N 629145600u  // (S-1)*T*B*CAT
#define NOISE_N 7864320u     // T*B*H

// ---------------- Threefry-2x32 (20 rounds), matches jax._src.prng ----------------
__host__ __device__ inline void tf2x32(uint32_t k0, uint32_t k1, uint32_t x0, uint32_t x1,
                                       uint32_t& o0, uint32_t& o1) {
  uint32_t ks2 = k0 ^ k1 ^ 0x1BD11BDAu;
  x0 += k0; x1 += k1;
#define TFR(r) do { x0 += x1; x1 = (x1 << r) | (x1 >> (32 - r)); x1 ^= x0; } while (0)
  TFR(13); TFR(15); TFR(26); TFR(6);
  x0 += k1; x1 += ks2 + 1u;
  TFR(17); TFR(29); TFR(16); TFR(24);
  x0 += ks2; x1 += k0 + 2u;
  TFR(13); TFR(15); TFR(26); TFR(6);
  x0 += k0; x1 += k1 + 3u;
  TFR(17); TFR(29); TFR(16); TFR(24);
  x0 += k1; x1 += ks2 + 4u;
  TFR(13); TFR(15); TFR(26); TFR(6);
  x0 += ks2; x1 += k0 + 5u;
#undef TFR
  o0 = x0; o1 = x1;
}

__device__ inline uint32_t jax_bits(uint32_t k0, uint32_t k1, uint32_t i, uint32_t n) {
#if JAX_PARTITIONABLE
  (void)n;
  uint32_t a, b;
  tf2x32(k0, k1, 0u, i, a, b);   // 64-bit iota counter: hi=0, lo=i
  return a ^ b;
#else
  uint32_t half = n >> 1;
  uint32_t lo = (i < half) ? i : (i - half);
  uint32_t a, b;
  tf2x32(k0, k1, lo, lo + half, a, b);
  return (i < half) ? a : b;
#endif
}

__device__ inline float bits_to_f01(uint32_t bits) {
  return __uint_as_float((bits >> 9) | 0x3f800000u) - 1.0f;
}

// erf_inv, CHLO/Giles f32 polynomial; w from double log (~correctly rounded)
__device__ inline float erfinv_f(float x) {
  double xd = (double)x;
  float w = (float)(-log((1.0 - xd) * (1.0 + xd)));
  float p;
  if (w < 5.0f) {
    w = __fadd_rn(w, -2.5f);
    p = 2.81022636e-08f;
    p = __fadd_rn(3.43273939e-07f, __fmul_rn(p, w));
    p = __fadd_rn(-3.5233877e-06f, __fmul_rn(p, w));
    p = __fadd_rn(-4.39150654e-06f, __fmul_rn(p, w));
    p = __fadd_rn(0.00021858087f, __fmul_rn(p, w));
    p = __fadd_rn(-0.00125372503f, __fmul_rn(p, w));
    p = __fadd_rn(-0.00417768164f, __fmul_rn(p, w));
    p = __fadd_rn(0.246640727f, __fmul_rn(p, w));
    p = __fadd_rn(1.50140941f, __fmul_rn(p, w));
  } else {
    w = __fadd_rn(__fsqrt_rn(w), -3.0f);
    p = -0.000200214257f;
    p = __fadd_rn(0.000100950558f, __fmul_rn(p, w));
    p = __fadd_rn(0.00134934322f, __fmul_rn(p, w));
    p = __fadd_rn(-0.00367342844f, __fmul_rn(p, w));
    p = __fadd_rn(0.00573950773f, __fmul_rn(p, w));
    p = __fadd_rn(-0.0076224613f, __fmul_rn(p, w));
    p = __fadd_rn(0.00943887047f, __fmul_rn(p, w));
    p = __fadd_rn(1.00167406f, __fmul_rn(p, w));
    p = __fadd_rn(2.83297682f, __fmul_rn(p, w));
  }
  return __fmul_rn(p, x);
}

// f32 gumbel: -log(-log(u)), accurate ocml logf (~1 ulp, same class as Eigen plog)
__device__ inline float gumbel_f32(uint32_t bits) {
  float f = bits_to_f01(bits);
  float u = fmaxf(f, 1.17549435e-38f);
  float l1 = logf(u);        // <= 0
  float g = -logf(-l1);
  return g;
}

__device__ inline uint32_t orderkey(float s) {
  uint32_t sb = __float_as_uint(s);
  return (sb & 0x80000000u) ? ~sb : (sb | 0x80000000u);
}

// ---------------- init ----------------
__global__ __launch_bounds__(512) void k_init(const float* __restrict__ hist,
                                              float* __restrict__ x0buf, int* __restrict__ ip) {
  int b = threadIdx.x;
  if (b < B_) {
    float tv = hist[b * 4800 + 5];
    int et = (int)tv;
    et = et < 0 ? 0 : (et > 9 ? 9 : et);
    const int mp[10] = {0, 1, 4, 2, 3, 4, 4, 4, 4, 4};
    ip[b] = et;
    ip[512 + b] = mp[et];
    x0buf[b * 2 + 0] = hist[b * 4800 + 49 * 6 + 0];
    x0buf[b * 2 + 1] = hist[b * 4800 + 49 * 6 + 1];
  }
  __syncthreads();
  if (b == 0) {
    int cnt[5] = {0, 0, 0, 0, 0};
    for (int i = 0; i < B_; i++) cnt[ip[512 + i]]++;
    int off[6];
    off[0] = 0;
    for (int e = 0; e < 5; e++) off[e + 1] = off[e] + cnt[e];
    int pos[5];
    for (int e = 0; e < 5; e++) pos[e] = off[e];
    for (int i = 0; i < B_; i++) { int e = ip[512 + i]; ip[1024 + pos[e]++] = i; }
    int* tbl = ip + 1536;
    int nrt = 0;
    for (int e = 0; e < 5; e++) {
      int n = cnt[e];
      for (int s = 0; s < n; s += 16) {
        tbl[1 + nrt] = e;
        tbl[37 + nrt] = off[e] + s;
        tbl[73 + nrt] = (n - s) < 16 ? (n - s) : 16;
        nrt++;
      }
    }
    tbl[0] = nrt;
  }
}

__global__ void k_zero(uint32_t* p, int n) {
  int i = blockIdx.x * blockDim.x + threadIdx.x;
  if (i < n) p[i] = 0u;
}

// ---------------- feature extractor (k-outer hoist; bitwise-identical accumulation order) ----------------
__global__ __launch_bounds__(256) void k_feat(const float* __restrict__ hist, const float* __restrict__ emb,
    const float* __restrict__ W1, const float* __restrict__ b1,
    const float* __restrict__ W2, const float* __restrict__ b2,
    const int* __restrict__ ip, float* __restrict__ featbuf) {
  __shared__ float xs[16][22];
  __shared__ float t1[16][H_];
  int row0 = blockIdx.x * 16;
  int tid = threadIdx.x;
  for (int idx = tid; idx < 16 * 22; idx += 256) {
    int r = idx / 22, c = idx % 22;
    int g = row0 + r;
    int b = g / SEQ_, s = g % SEQ_;
    xs[r][c] = (c < 6) ? hist[b * 4800 + s * 6 + c] : emb[ip[b] * EMB_ + (c - 6)];
  }
  __syncthreads();
  int j = tid;
  {
    double acc[16];
    for (int r = 0; r < 16; r++) acc[r] = 0.0;
    for (int k = 0; k < 22; k++) {
      double w = (double)W1[k * H_ + j];
      for (int r = 0; r < 16; r++) acc[r] += (double)xs[r][k] * w;
    }
    double bb = (double)b1[j];
    for (int r = 0; r < 16; r++) t1[r][j] = fmaxf((float)(acc[r] + bb), 0.0f);
  }
  __syncthreads();
  {
    double acc[16];
    for (int r = 0; r < 16; r++) acc[r] = 0.0;
    for (int k = 0; k < H_; k++) {
      double w = (double)W2[k * H_ + j];
      for (int r = 0; r < 16; r++) acc[r] += (double)t1[r][k] * w;
    }
    double bb = (double)b2[j];
    for (int r = 0; r < 16; r++) {
      float v = (float)(acc[r] + bb);
      int g = row0 + r;
      int b = g / SEQ_, s = g % SEQ_;
      featbuf[(size_t)s * (B_ * H_) + (size_t)b * H_ + j] = v;
    }
  }
}

// ---------------- generic GRU step (unchanged) ----------------
template <int D1, bool GROUPED>
__global__ __launch_bounds__(256) void k_gru(
    const float* __restrict__ x, const float* __restrict__ hin,
    float* __restrict__ hout, float* __restrict__ ys,
    const float* __restrict__ Wih_base, const float* __restrict__ Whh_base,
    const float* __restrict__ bih_base, const float* __restrict__ bhh_base,
    int layer, const int* __restrict__ ip) {
  __shared__ float xs[16][(D1 == 2) ? 2 : H_];
  __shared__ float hs[16][H_];
  __shared__ int rowb[16];
  int bx = blockIdx.x, by = blockIdx.y;
  const int* tbl = ip + 1536;
  const int* order = ip + 1024;
  int e = 0, start, nr;
  if (GROUPED) {
    int nrt = tbl[0];
    if (bx >= nrt) return;
    e = tbl[1 + bx];
    start = tbl[37 + bx];
    nr = tbl[73 + bx];
  } else {
    start = bx * 16;
    nr = 16;
  }
  int tid = threadIdx.x;
  for (int idx = tid; idx < 16 * H_; idx += 256) {
    int r = idx >> 8;
    int k = idx & 255;
    int rr = (r < nr) ? r : 0;
    int b = GROUPED ? order[start + rr] : (start + rr);
    if (k == 0) rowb[r] = b;
    hs[r][k] = hin[b * H_ + k];
    if (D1 == H_) xs[r][k] = x[b * H_ + k];
    else if (k < D1) xs[r][k] = x[b * D1 + k];
  }
  __syncthreads();
  size_t woff = (size_t)(GROUPED ? (e * NL_ + layer) : 0);
  const float* Wih = Wih_base + woff * (size_t)D1 * TG_;
  const float* Whh = Whh_base + woff * (size_t)H_ * TG_;
  const float* bih = bih_base + woff * TG_;
  const float* bhh = bhh_base + woff * TG_;
  int j = tid & 31, rs = tid >> 5;
  int hc = by * 32 + j;
  int cr = hc, cz = H_ + hc, cn = 2 * H_ + hc;
  double ra0 = 0, ra1 = 0, za0 = 0, za1 = 0, ni0 = 0, ni1 = 0, nh0 = 0, nh1 = 0;
  for (int k = 0; k < H_; k++) {
    float wrh = Whh[k * TG_ + cr], wzh = Whh[k * TG_ + cz], wnh = Whh[k * TG_ + cn];
    float h0v = hs[rs][k], h1v = hs[rs + 8][k];
    ra0 += (double)h0v * wrh; ra1 += (double)h1v * wrh;
    za0 += (double)h0v * wzh; za1 += (double)h1v * wzh;
    nh0 += (double)h0v * wnh; nh1 += (double)h1v * wnh;
    if (D1 == H_) {
      float wri = Wih[k * TG_ + cr], wzi = Wih[k * TG_ + cz], wni = Wih[k * TG_ + cn];
      float x0v = xs[rs][k], x1v = xs[rs + 8][k];
      ra0 += (double)x0v * wri; ra1 += (double)x1v * wri;
      za0 += (double)x0v * wzi; za1 += (double)x1v * wzi;
      ni0 += (double)x0v * wni; ni1 += (double)x1v * wni;
    }
  }
  if (D1 != H_) {
    for (int k = 0; k < D1; k++) {
      float wri = Wih[k * TG_ + cr], wzi = Wih[k * TG_ + cz], wni = Wih[k * TG_ + cn];
      float x0v = xs[rs][k], x1v = xs[rs + 8][k];
      ra0 += (double)x0v * wri; ra1 += (double)x1v * wri;
      za0 += (double)x0v * wzi; za1 += (double)x1v * wzi;
      ni0 += (double)x0v * wni; ni1 += (double)x1v * wni;
    }
  }
  double br_i = (double)bih[cr], bz_i = (double)bih[cz], bn_i = (double)bih[cn];
  double br_h = (double)bhh[cr], bz_h = (double)bhh[cz], bn_h = (double)bhh[cn];
  for (int p = 0; p < 2; p++) {
    int r = rs + 8 * p;
    if (r >= nr) continue;
    double ra = p ? ra1 : ra0, za = p ? za1 : za0, ni = p ? ni1 : ni0, nh = p ? nh1 : nh0;
    double rr = 1.0 / (1.0 + exp(-(ra + br_i + br_h)));
    double zz = 1.0 / (1.0 + exp(-(za + bz_i + bz_h)));
    double nn = tanh((ni + bn_i) + rr * (nh + bn_h));
    double hv = (double)hs[r][hc];
    float hnew = (float)((1.0 - zz) * nn + zz * hv);
    int b = rowb[r];
    hout[b * H_ + hc] = hnew;
    if (ys) ys[b * H_ + hc] = hnew;
  }
}

// ---------------- heads (unchanged) ----------------
__global__ __launch_bounds__(256) void k_heads(const float* __restrict__ lh,
    const float* __restrict__ hgW1, const float* __restrict__ hgb1,
    const float* __restrict__ hgW2, const float* __restrict__ hgb2,
    const float* __restrict__ hgW3, const float* __restrict__ hgb3,
    const float* __restrict__ ceW1, const float* __restrict__ ceb1,
    const float* __restrict__ ceW2, const float* __restrict__ ceb2,
    float* __restrict__ out) {
  __shared__ float hsm[16][H_];
  __shared__ float t1[16][H_];
  __shared__ float t2[16][H2_];
  __shared__ float c2s[16][T_];
  int row0 = blockIdx.x * 16;
  int tid = threadIdx.x;
  for (int idx = tid; idx < 16 * H_; idx += 256) {
    int r = idx >> 8, k = idx & 255;
    hsm[r][k] = lh[(size_t)(row0 + r) * H_ + k];
  }
  __syncthreads();
  {
    int j = tid;
    for (int r = 0; r < 16; r++) {
      double a = 0;
      for (int k = 0; k < H_; k++) a += (double)hsm[r][k] * (double)hgW1[k * H_ + j];
      t1[r][j] = fmaxf((float)(a + (double)hgb1[j]), 0.0f);
    }
  }
  __syncthreads();
  if (tid < H2_) {
    int j = tid;
    for (int r = 0; r < 16; r++) {
      double a = 0;
      for (int k = 0; k < H_; k++) a += (double)t1[r][k] * (double)hgW2[k * H2_ + j];
      t2[r][j] = fmaxf((float)(a + (double)hgb2[j]), 0.0f);
    }
  }
  __syncthreads();
  if (tid < 2 * T_) {
    int j = tid;
    for (int r = 0; r < 16; r++) {
      double a = 0;
      for (int k = 0; k < H2_; k++) a += (double)t2[r][k] * (double)hgW3[k * (2 * T_) + j];
      float v = (float)(a + (double)hgb3[j]);
      int b = row0 + r;
      int t = j >> 1, c = j & 1;
      out[(((size_t)b * S_ + 0) * T_ + t) * 2 + c] = v;
    }
  }
  __syncthreads();
  if (tid < H2_) {
    int j = tid;
    for (int r = 0; r < 16; r++) {
      double a = 0;
      for (int k = 0; k < H_; k++) a += (double)hsm[r][k] * (double)ceW1[k * H2_ + j];
      t2[r][j] = fmaxf((float)(a + (double)ceb1[j]), 0.0f);
    }
  }
  __syncthreads();
  if (tid < T_) {
    int j = tid;
    for (int r = 0; r < 16; r++) {
      double a = 0;
      for (int k = 0; k < H2_; k++) a += (double)t2[r][k] * (double)ceW2[k * T_ + j];
      c2s[r][j] = (float)(a + (double)ceb2[j]);
    }
  }
  __syncthreads();
  if (tid < 16) {
    int r = tid;
    int b = row0 + r;
    double s = 0;
    for (int j = 0; j < T_; j++) s += (double)c2s[r][j];
    float m = (float)(s / 60.0);
    for (int sd = 0; sd < S_; sd++) {
      float d = (float)pow((double)0.9f, (double)sd);
      out[368640 + b * S_ + sd] = __fmul_rn(m, d);
    }
  }
}

// ---------------- hp layer1 (unchanged) ----------------
__global__ __launch_bounds__(256) void k_hp1(const float* __restrict__ lh,
    const float* __restrict__ W1, const float* __restrict__ b1,
    float* __restrict__ h1buf, uint32_t nk0, uint32_t nk1) {
  __shared__ float th[16][H_];
  int row0 = blockIdx.x * 16;
  int tid = threadIdx.x;
  const float SQRT2F = 1.4142135623730951f;
  const float LO = -0x1.fffffep-1f;
  for (int idx = tid; idx < 16 * H_; idx += 256) {
    int r = idx >> 8, k = idx & 255;
    int g = row0 + r;
    int t = g / B_, b = g % B_;
    uint32_t i = ((uint32_t)t * B_ + (uint32_t)b) * H_ + (uint32_t)k;
    uint32_t bits = jax_bits(nk0, nk1, i, NOISE_N);
    float f = bits_to_f01(bits);
    float u = fmaxf(LO, __fadd_rn(__fmul_rn(f, 2.0f), LO));
    float nz = __fmul_rn(SQRT2F, erfinv_f(u));
    float sc = __fdiv_rn(__fmul_rn(0.1f, (float)t), 60.0f);
    th[r][k] = __fadd_rn(lh[(size_t)b * H_ + k], __fmul_rn(nz, sc));
  }
  __syncthreads();
  int j = tid;
  double acc[16];
  for (int r = 0; r < 16; r++) acc[r] = 0.0;
  for (int k = 0; k < H_; k++) {
    double w = (double)W1[k * H_ + j];
    for (int r = 0; r < 16; r++) acc[r] += (double)th[r][k] * w;
  }
  double bb = (double)b1[j];
  for (int r = 0; r < 16; r++)
    h1buf[(size_t)(row0 + r) * H_ + j] = fmaxf((float)(acc[r] + bb), 0.0f);
}

// ---------------- hp layer2 + gumbel + argmax (f32 rewrite) ----------------
// block: 16 rows (one t) x 128 cats. 4 waves; wave w owns rows 4w..4w+3.
// lane owns cats {cat0+2*lane, cat0+2*lane+1} -> float2 W2 loads.
__global__ __launch_bounds__(256) void k_hp2(const float* __restrict__ h1buf,
    const float* __restrict__ W2, const float* __restrict__ b2,
    unsigned long long* __restrict__ samples, uint32_t sk0, uint32_t sk1) {
  __shared__ float h1[16][H_];
  int row0 = blockIdx.x * 16;
  int cat0 = blockIdx.y * 128;
  int tid = threadIdx.x;
  for (int idx = tid; idx < 16 * H_ / 4; idx += 256) {
    int r = idx >> 6, k4 = (idx & 63) << 2;
    *(float4*)&h1[r][k4] = *(const float4*)&h1buf[(size_t)(row0 + r) * H_ + k4];
  }
  __syncthreads();
  int wave = tid >> 6;
  int lane = tid & 63;
  int catA = cat0 + 2 * lane;
  int rbase = 4 * wave;

  float acc[4][2];
  for (int q = 0; q < 4; q++) { acc[q][0] = 0.0f; acc[q][1] = 0.0f; }
  const float* w2p = W2 + catA;
  for (int k = 0; k < H_; k += 4) {
    float4 hv0 = *(const float4*)&h1[rbase + 0][k];
    float4 hv1 = *(const float4*)&h1[rbase + 1][k];
    float4 hv2 = *(const float4*)&h1[rbase + 2][k];
    float4 hv3 = *(const float4*)&h1[rbase + 3][k];
#pragma unroll
    for (int kk = 0; kk < 4; kk++) {
      float2 w = *(const float2*)&w2p[(size_t)(k + kk) * CAT_];
      float h0 = (&hv0.x)[kk], h1v = (&hv1.x)[kk], h2 = (&hv2.x)[kk], h3 = (&hv3.x)[kk];
      acc[0][0] = __fmaf_rn(h0, w.x, acc[0][0]); acc[0][1] = __fmaf_rn(h0, w.y, acc[0][1]);
      acc[1][0] = __fmaf_rn(h1v, w.x, acc[1][0]); acc[1][1] = __fmaf_rn(h1v, w.y, acc[1][1]);
      acc[2][0] = __fmaf_rn(h2, w.x, acc[2][0]); acc[2][1] = __fmaf_rn(h2, w.y, acc[2][1]);
      acc[3][0] = __fmaf_rn(h3, w.x, acc[3][0]); acc[3][1] = __fmaf_rn(h3, w.y, acc[3][1]);
    }
  }
  float lg[4][2];
  float b0 = b2[catA], b1v = b2[catA + 1];
  for (int q = 0; q < 4; q++) {
    lg[q][0] = __fadd_rn(acc[q][0], b0);
    lg[q][1] = __fadd_rn(acc[q][1], b1v);
  }

  int t = row0 / B_;
  int bbase = row0 % B_;
#pragma unroll
  for (int s = 0; s < S_ - 1; s++) {
#pragma unroll
    for (int q = 0; q < 4; q++) {
      int brow = bbase + rbase + q;
      uint32_t ibase = (((uint32_t)s * T_ + (uint32_t)t) * B_ + (uint32_t)brow) * CAT_ + (uint32_t)catA;
      float g0 = gumbel_f32(jax_bits(sk0, sk1, ibase, GUMBEL_N));
      float g1 = gumbel_f32(jax_bits(sk0, sk1, ibase + 1u, GUMBEL_N));
      float s0 = __fadd_rn(g0, lg[q][0]);
      float s1 = __fadd_rn(g1, lg[q][1]);
      uint32_t k0 = orderkey(s0), k1 = orderkey(s1);
      uint32_t bestk; int bestc;
      if (k1 > k0) { bestk = k1; bestc = catA + 1; }
      else         { bestk = k0; bestc = catA; }
      uint32_t m = bestk;
      for (int off = 1; off < 64; off <<= 1) {
        uint32_t o = __shfl_xor(m, off, 64);
        m = m > o ? m : o;
      }
      unsigned long long mask = __ballot(bestk == m);
      int src = __ffsll(mask) - 1;
      int wcat = __shfl(bestc, src, 64);
      if (lane == 0) {
        unsigned long long p =
            (((unsigned long long)m) << 32) | (unsigned long long)(~(uint32_t)wcat);
        atomicMax(&samples[((size_t)s * T_ + t) * B_ + brow], p);
      }
    }
  }
}

// ---------------- decode samples -> grid points ----------------
__global__ void k_emit(const unsigned long long* __restrict__ samples, float* __restrict__ out) {
  int gid = blockIdx.x * blockDim.x + threadIdx.x;
  if (gid >= (S_ - 1) * T_ * B_) return;
  int b = gid % B_;
  int t = (gid / B_) % T_;
  int s = gid / (B_ * T_);
  unsigned long long v = samples[gid];
  uint32_t cat = ~(uint32_t)(v & 0xFFFFFFFFu);
  float xi = (float)(cat & 63u);
  float yi = (float)(cat >> 6);
  float px = -50.0f + xi * 1.5625f + 0.78125f;
  float py = -50.0f + yi * 1.5625f + 0.78125f;
  size_t o = (((size_t)b * S_ + (size_t)(s + 1)) * T_ + t) * 2;
  out[o] = px;
  out[o + 1] = py;
}

// ---------------- host ----------------
extern "C" void kernel_launch(void* const* d_in, const int* in_sizes, int n_in,
                              void* d_out, int out_size, void* d_ws, size_t ws_size,
                              hipStream_t stream) {
  (void)in_sizes; (void)n_in; (void)out_size; (void)ws_size;
  const float* hist   = (const float*)d_in[0];
  const float* emb    = (const float*)d_in[1];
  const float* feW1   = (const float*)d_in[2];
  const float* feb1   = (const float*)d_in[3];
  const float* feW2   = (const float*)d_in[4];
  const float* feb2   = (const float*)d_in[5];
  const float* encWih = (const float*)d_in[6];
  const float* encWhh = (const float*)d_in[7];
  const float* encbih = (const float*)d_in[8];
  const float* encbhh = (const float*)d_in[9];
  const float* dWih0  = (const float*)d_in[10];
  const float* dWhh0  = (const float*)d_in[11];
  const float* dbih0  = (const float*)d_in[12];
  const float* dbhh0  = (const float*)d_in[13];
  const float* dWih1  = (const float*)d_in[14];
  const float* dWhh1  = (const float*)d_in[15];
  const float* dbih1  = (const float*)d_in[16];
  const float* dbhh1  = (const float*)d_in[17];
  const float* hgW1   = (const float*)d_in[18];
  const float* hgb1   = (const float*)d_in[19];
  const float* hgW2   = (const float*)d_in[20];
  const float* hgb2   = (const float*)d_in[21];
  const float* hgW3   = (const float*)d_in[22];
  const float* hgb3   = (const float*)d_in[23];
  const float* ceW1   = (const float*)d_in[24];
  const float* ceb1   = (const float*)d_in[25];
  const float* ceW2   = (const float*)d_in[26];
  const float* ceb2   = (const float*)d_in[27];
  const float* hpW1   = (const float*)d_in[28];
  const float* hpb1   = (const float*)d_in[29];
  const float* hpW2   = (const float*)d_in[30];
  const float* hpb2   = (const float*)d_in[31];
  float* out = (float*)d_out;
  float* ws = (float*)d_ws;

  float* feat  = ws;
  float* ys0   = ws + 6553600;
  float* h1hp  = ws;
  float* hA0   = ws + 13107200;
  float* hB0   = hA0 + 131072;
  float* hA1   = hB0 + 131072;
  float* hB1   = hA1 + 131072;
  float* dech0 = hB1 + 131072;
  float* lh    = dech0 + 131072;
  float* x0buf = lh + 131072;
  int*   ip    = (int*)(x0buf + 1024);
  unsigned long long* samples =
      (unsigned long long*)(((uintptr_t)(ip + 2048) + 255) & ~(uintptr_t)255);

  uint32_t kn0, kn1, ks0, ks1;
#if JAX_PARTITIONABLE
  tf2x32(0u, 42u, 0u, 0u, kn0, kn1);
  tf2x32(0u, 42u, 0u, 1u, ks0, ks1);
#else
  { uint32_t a0, a1, b0, b1;
    tf2x32(0u, 42u, 0u, 2u, a0, a1);
    tf2x32(0u, 42u, 1u, 3u, b0, b1);
    kn0 = a0; kn1 = b0; ks0 = a1; ks1 = b1; }
#endif

  k_init<<<dim3(1), dim3(512), 0, stream>>>(hist, x0buf, ip);
  k_zero<<<dim3((524288 + 255) / 256), dim3(256), 0, stream>>>((uint32_t*)hA0, 524288);
  k_zero<<<dim3((307200 + 255) / 256), dim3(256), 0, stream>>>((uint32_t*)samples, 307200);
  k_feat<<<dim3(1600), dim3(256), 0, stream>>>(hist, emb, feW1, feb1, feW2, feb2, ip, feat);

  float* hin = hA0; float* hout = hB0;
  for (int t = 0; t < SEQ_; t++) {
    k_gru<H_, true><<<dim3(36, 8), dim3(256), 0, stream>>>(
        feat + (size_t)t * 131072, hin, hout, ys0 + (size_t)t * 131072,
        encWih, encWhh, encbih, encbhh, 0, ip);
    float* tmp = hin; hin = hout; hout = tmp;
  }
  float* ench0 = hin;
  float* hin1 = hA1; float* hout1 = hB1;
  for (int t = 0; t < SEQ_; t++) {
    k_gru<H_, true><<<dim3(36, 8), dim3(256), 0, stream>>>(
        ys0 + (size_t)t * 131072, hin1, hout1, nullptr,
        encWih, encWhh, encbih, encbhh, 1, ip);
    float* tmp = hin1; hin1 = hout1; hout1 = tmp;
  }
  float* ench1 = hin1;

  k_gru<2, false><<<dim3(32, 8), dim3(256), 0, stream>>>(
      x0buf, ench0, dech0, nullptr, dWih0, dWhh0, dbih0, dbhh0, 0, ip);
  k_gru<H_, false><<<dim3(32, 8), dim3(256), 0, stream>>>(
      dech0, ench1, lh, nullptr, dWih1, dWhh1, dbih1, dbhh1, 0, ip);

  k_heads<<<dim3(32), dim3(256), 0, stream>>>(lh, hgW1, hgb1, hgW2, hgb2, hgW3, hgb3,
                                              ceW1, ceb1, ceW2, ceb2, out);
  k_hp1<<<dim3(1920), dim3(256), 0, stream>>>(lh, hpW1, hpb1, h1hp, kn0, kn1);
  k_hp2<<<dim3(1920, 32), dim3(256), 0, stream>>>(h1hp, hpW2, hpb2, samples, ks0, ks1);
  k_emit<<<dim3(600), dim3(256), 0, stream>>>(samples, out);
}

// Round 3
// 6114.775 us; speedup vs baseline: 2.3210x; 1.5771x over previous
//
#include <hip/hip_runtime.h>
#include <stdint.h>
#include <math.h>

#define JAX_PARTITIONABLE 1

#define B_ 512
#define SEQ_ 50
#define H_ 256
#define H2_ 128
#define T_ 60
#define S_ 6
#define EMB_ 16
#define NL_ 2
#define TG_ 768     // 3*H
#define CAT_ 4096   // G*G
#define GUMBEL_N 629145600u  // (S-1)*T*B*CAT
#define NOISE_N 7864320u     // T*B*H

// ---------------- Threefry-2x32 (20 rounds), matches jax._src.prng ----------------
__host__ __device__ inline void tf2x32(uint32_t k0, uint32_t k1, uint32_t x0, uint32_t x1,
                                       uint32_t& o0, uint32_t& o1) {
  uint32_t ks2 = k0 ^ k1 ^ 0x1BD11BDAu;
  x0 += k0; x1 += k1;
#define TFR(r) do { x0 += x1; x1 = (x1 << r) | (x1 >> (32 - r)); x1 ^= x0; } while (0)
  TFR(13); TFR(15); TFR(26); TFR(6);
  x0 += k1; x1 += ks2 + 1u;
  TFR(17); TFR(29); TFR(16); TFR(24);
  x0 += ks2; x1 += k0 + 2u;
  TFR(13); TFR(15); TFR(26); TFR(6);
  x0 += k0; x1 += k1 + 3u;
  TFR(17); TFR(29); TFR(16); TFR(24);
  x0 += k1; x1 += ks2 + 4u;
  TFR(13); TFR(15); TFR(26); TFR(6);
  x0 += ks2; x1 += k0 + 5u;
#undef TFR
  o0 = x0; o1 = x1;
}

__device__ inline uint32_t jax_bits(uint32_t k0, uint32_t k1, uint32_t i, uint32_t n) {
#if JAX_PARTITIONABLE
  (void)n;
  uint32_t a, b;
  tf2x32(k0, k1, 0u, i, a, b);   // 64-bit iota counter: hi=0, lo=i
  return a ^ b;
#else
  uint32_t half = n >> 1;
  uint32_t lo = (i < half) ? i : (i - half);
  uint32_t a, b;
  tf2x32(k0, k1, lo, lo + half, a, b);
  return (i < half) ? a : b;
#endif
}

__device__ inline float bits_to_f01(uint32_t bits) {
  return __uint_as_float((bits >> 9) | 0x3f800000u) - 1.0f;
}

// erf_inv, CHLO/Giles f32 polynomial; w from double log (~correctly rounded)
__device__ inline float erfinv_f(float x) {
  double xd = (double)x;
  float w = (float)(-log((1.0 - xd) * (1.0 + xd)));
  float p;
  if (w < 5.0f) {
    w = __fadd_rn(w, -2.5f);
    p = 2.81022636e-08f;
    p = __fadd_rn(3.43273939e-07f, __fmul_rn(p, w));
    p = __fadd_rn(-3.5233877e-06f, __fmul_rn(p, w));
    p = __fadd_rn(-4.39150654e-06f, __fmul_rn(p, w));
    p = __fadd_rn(0.00021858087f, __fmul_rn(p, w));
    p = __fadd_rn(-0.00125372503f, __fmul_rn(p, w));
    p = __fadd_rn(-0.00417768164f, __fmul_rn(p, w));
    p = __fadd_rn(0.246640727f, __fmul_rn(p, w));
    p = __fadd_rn(1.50140941f, __fmul_rn(p, w));
  } else {
    w = __fadd_rn(__fsqrt_rn(w), -3.0f);
    p = -0.000200214257f;
    p = __fadd_rn(0.000100950558f, __fmul_rn(p, w));
    p = __fadd_rn(0.00134934322f, __fmul_rn(p, w));
    p = __fadd_rn(-0.00367342844f, __fmul_rn(p, w));
    p = __fadd_rn(0.00573950773f, __fmul_rn(p, w));
    p = __fadd_rn(-0.0076224613f, __fmul_rn(p, w));
    p = __fadd_rn(0.00943887047f, __fmul_rn(p, w));
    p = __fadd_rn(1.00167406f, __fmul_rn(p, w));
    p = __fadd_rn(2.83297682f, __fmul_rn(p, w));
  }
  return __fmul_rn(p, x);
}

// f32 gumbel: -log(-log(u)), accurate ocml logf
__device__ inline float gumbel_f32(uint32_t bits) {
  float f = bits_to_f01(bits);
  float u = fmaxf(f, 1.17549435e-38f);
  float l1 = logf(u);
  float g = -logf(-l1);
  return g;
}

__device__ inline uint32_t orderkey(float s) {
  uint32_t sb = __float_as_uint(s);
  return (sb & 0x80000000u) ? ~sb : (sb | 0x80000000u);
}

// ---------------- init ----------------
__global__ __launch_bounds__(512) void k_init(const float* __restrict__ hist,
                                              float* __restrict__ x0buf, int* __restrict__ ip) {
  int b = threadIdx.x;
  if (b < B_) {
    float tv = hist[b * 4800 + 5];
    int et = (int)tv;
    et = et < 0 ? 0 : (et > 9 ? 9 : et);
    const int mp[10] = {0, 1, 4, 2, 3, 4, 4, 4, 4, 4};
    ip[b] = et;
    ip[512 + b] = mp[et];
    x0buf[b * 2 + 0] = hist[b * 4800 + 49 * 6 + 0];
    x0buf[b * 2 + 1] = hist[b * 4800 + 49 * 6 + 1];
  }
  __syncthreads();
  if (b == 0) {
    int cnt[5] = {0, 0, 0, 0, 0};
    for (int i = 0; i < B_; i++) cnt[ip[512 + i]]++;
    int off[6];
    off[0] = 0;
    for (int e = 0; e < 5; e++) off[e + 1] = off[e] + cnt[e];
    int pos[5];
    for (int e = 0; e < 5; e++) pos[e] = off[e];
    for (int i = 0; i < B_; i++) { int e = ip[512 + i]; ip[1024 + pos[e]++] = i; }
    int* tbl = ip + 1536;
    int nrt = 0;
    for (int e = 0; e < 5; e++) {
      int n = cnt[e];
      for (int s = 0; s < n; s += 16) {
        tbl[1 + nrt] = e;
        tbl[37 + nrt] = off[e] + s;
        tbl[73 + nrt] = (n - s) < 16 ? (n - s) : 16;
        nrt++;
      }
    }
    tbl[0] = nrt;
  }
}

__global__ void k_zero(uint32_t* p, int n) {
  int i = blockIdx.x * blockDim.x + threadIdx.x;
  if (i < n) p[i] = 0u;
}

// ---------------- feature extractor ----------------
__global__ __launch_bounds__(256) void k_feat(const float* __restrict__ hist, const float* __restrict__ emb,
    const float* __restrict__ W1, const float* __restrict__ b1,
    const float* __restrict__ W2, const float* __restrict__ b2,
    const int* __restrict__ ip, float* __restrict__ featbuf) {
  __shared__ float xs[16][22];
  __shared__ float t1[16][H_];
  int row0 = blockIdx.x * 16;
  int tid = threadIdx.x;
  for (int idx = tid; idx < 16 * 22; idx += 256) {
    int r = idx / 22, c = idx % 22;
    int g = row0 + r;
    int b = g / SEQ_, s = g % SEQ_;
    xs[r][c] = (c < 6) ? hist[b * 4800 + s * 6 + c] : emb[ip[b] * EMB_ + (c - 6)];
  }
  __syncthreads();
  int j = tid;
  {
    double acc[16];
    for (int r = 0; r < 16; r++) acc[r] = 0.0;
    for (int k = 0; k < 22; k++) {
      double w = (double)W1[k * H_ + j];
      for (int r = 0; r < 16; r++) acc[r] += (double)xs[r][k] * w;
    }
    double bb = (double)b1[j];
    for (int r = 0; r < 16; r++) t1[r][j] = fmaxf((float)(acc[r] + bb), 0.0f);
  }
  __syncthreads();
  {
    double acc[16];
    for (int r = 0; r < 16; r++) acc[r] = 0.0;
    for (int k = 0; k < H_; k++) {
      double w = (double)W2[k * H_ + j];
      for (int r = 0; r < 16; r++) acc[r] += (double)t1[r][k] * w;
    }
    double bb = (double)b2[j];
    for (int r = 0; r < 16; r++) {
      float v = (float)(acc[r] + bb);
      int g = row0 + r;
      int b = g / SEQ_, s = g % SEQ_;
      featbuf[(size_t)s * (B_ * H_) + (size_t)b * H_ + j] = v;
    }
  }
}

// ---------------- pipelined encoder: GI (x-part, batched) + light step (h-part) ----------------
// gi_block: gi[b][c] = (x @ Wih[e,layer])[c] + bih[c], f64 acc, f32 store.
__device__ __forceinline__ void gi_block(float (*xs)[H_], int* rowb,
    int rt, int cg, int tid,
    const float* __restrict__ x, float* __restrict__ gi_out,
    const float* __restrict__ Wih_base, const float* __restrict__ bih_base,
    int layer, const int* __restrict__ ip) {
  const int* tbl = ip + 1536;
  const int* order = ip + 1024;
  int nrt = tbl[0];
  if (rt >= nrt) return;
  int e = tbl[1 + rt];
  int start = tbl[37 + rt];
  int nr = tbl[73 + rt];
  for (int idx = tid; idx < 16 * H_; idx += 256) {
    int r = idx >> 8, k = idx & 255;
    int rr = (r < nr) ? r : 0;
    int b = order[start + rr];
    if (k == 0) rowb[r] = b;
    xs[r][k] = x[b * H_ + k];
  }
  __syncthreads();
  size_t woff = (size_t)(e * NL_ + layer);
  const float* Wih = Wih_base + woff * (size_t)H_ * TG_;
  const float* bih = bih_base + woff * TG_;
  int j = tid & 31, rs = tid >> 5;
  int c = cg * 32 + j;
  int cr = c, cz = H_ + c, cn = 2 * H_ + c;
  double ar0 = 0, ar1 = 0, az0 = 0, az1 = 0, an0 = 0, an1 = 0;
  for (int k = 0; k < H_; k++) {
    float wr = Wih[k * TG_ + cr], wz = Wih[k * TG_ + cz], wn = Wih[k * TG_ + cn];
    float x0 = xs[rs][k], x1 = xs[rs + 8][k];
    ar0 += (double)x0 * wr; ar1 += (double)x1 * wr;
    az0 += (double)x0 * wz; az1 += (double)x1 * wz;
    an0 += (double)x0 * wn; an1 += (double)x1 * wn;
  }
  double br = (double)bih[cr], bz = (double)bih[cz], bn = (double)bih[cn];
  for (int p = 0; p < 2; p++) {
    int r = rs + 8 * p;
    if (r >= nr) continue;
    int b = rowb[r];
    gi_out[b * TG_ + cr] = (float)((p ? ar1 : ar0) + br);
    gi_out[b * TG_ + cz] = (float)((p ? az1 : az0) + bz);
    gi_out[b * TG_ + cn] = (float)((p ? an1 : an0) + bn);
  }
}

// step_block: gh = h @ Whh[e,layer]; hnew via gates using precomputed gi (+bih) and bhh.
__device__ __forceinline__ void step_block(float (*hs)[H_], int* rowb,
    int rt, int cg, int tid,
    const float* __restrict__ gi_in, const float* __restrict__ hin,
    float* __restrict__ hout, float* __restrict__ ys,
    const float* __restrict__ Whh_base, const float* __restrict__ bhh_base,
    int layer, const int* __restrict__ ip) {
  const int* tbl = ip + 1536;
  const int* order = ip + 1024;
  int nrt = tbl[0];
  if (rt >= nrt) return;
  int e = tbl[1 + rt];
  int start = tbl[37 + rt];
  int nr = tbl[73 + rt];
  for (int idx = tid; idx < 16 * H_; idx += 256) {
    int r = idx >> 8, k = idx & 255;
    int rr = (r < nr) ? r : 0;
    int b = order[start + rr];
    if (k == 0) rowb[r] = b;
    hs[r][k] = hin[b * H_ + k];
  }
  __syncthreads();
  size_t woff = (size_t)(e * NL_ + layer);
  const float* Whh = Whh_base + woff * (size_t)H_ * TG_;
  const float* bhh = bhh_base + woff * TG_;
  int j = tid & 31, rs = tid >> 5;
  int c = cg * 32 + j;
  int cr = c, cz = H_ + c, cn = 2 * H_ + c;
  double gr0 = 0, gr1 = 0, gz0 = 0, gz1 = 0, gn0 = 0, gn1 = 0;
  for (int k = 0; k < H_; k++) {
    float wr = Whh[k * TG_ + cr], wz = Whh[k * TG_ + cz], wn = Whh[k * TG_ + cn];
    float h0 = hs[rs][k], h1 = hs[rs + 8][k];
    gr0 += (double)h0 * wr; gr1 += (double)h1 * wr;
    gz0 += (double)h0 * wz; gz1 += (double)h1 * wz;
    gn0 += (double)h0 * wn; gn1 += (double)h1 * wn;
  }
  double bhr = (double)bhh[cr], bhz = (double)bhh[cz], bhn = (double)bhh[cn];
  for (int p = 0; p < 2; p++) {
    int r = rs + 8 * p;
    if (r >= nr) continue;
    int b = rowb[r];
    double gir = (double)gi_in[b * TG_ + cr];
    double giz = (double)gi_in[b * TG_ + cz];
    double gin = (double)gi_in[b * TG_ + cn];
    double ghr = (p ? gr1 : gr0) + bhr;
    double ghz = (p ? gz1 : gz0) + bhz;
    double ghn = (p ? gn1 : gn0) + bhn;
    double rr = 1.0 / (1.0 + exp(-(gir + ghr)));
    double zz = 1.0 / (1.0 + exp(-(giz + ghz)));
    double nn = tanh(gin + rr * ghn);
    double hv = (double)hs[r][c];
    float hnew = (float)((1.0 - zz) * nn + zz * hv);
    hout[b * H_ + c] = hnew;
    if (ys) ys[b * H_ + c] = hnew;
  }
}

// dispatch d: grp0 GI0[t=d], grp1 L0-step[t=d-1], grp2 GI1[t=d-2], grp3 L1-step[t=d-3]
__global__ __launch_bounds__(256) void k_pipe(int d,
    const float* __restrict__ feat, float* __restrict__ ys0,
    float* __restrict__ gi0, float* __restrict__ gi1,
    float* __restrict__ h0A, float* __restrict__ h0B,
    float* __restrict__ h1A, float* __restrict__ h1B,
    const float* __restrict__ Wih, const float* __restrict__ Whh,
    const float* __restrict__ bih, const float* __restrict__ bhh,
    const int* __restrict__ ip) {
  __shared__ float sb[16][H_];
  __shared__ int rowb[16];
  int g = blockIdx.x;
  int grp = g / 288, bx = g % 288;
  int rt = bx >> 3, cg = bx & 7;
  int tid = threadIdx.x;
  if (grp == 0) {
    int t = d; if (t >= SEQ_) return;
    gi_block(sb, rowb, rt, cg, tid, feat + (size_t)t * 131072,
             gi0 + (size_t)(t & 1) * 393216, Wih, bih, 0, ip);
  } else if (grp == 1) {
    int t = d - 1; if (t < 0 || t >= SEQ_) return;
    const float* hin = (t & 1) ? h0B : h0A;
    float* hout = (t & 1) ? h0A : h0B;
    step_block(sb, rowb, rt, cg, tid, gi0 + (size_t)(t & 1) * 393216,
               hin, hout, ys0 + (size_t)t * 131072, Whh, bhh, 0, ip);
  } else if (grp == 2) {
    int t = d - 2; if (t < 0 || t >= SEQ_) return;
    gi_block(sb, rowb, rt, cg, tid, ys0 + (size_t)t * 131072,
             gi1 + (size_t)(t & 1) * 393216, Wih, bih, 1, ip);
  } else {
    int t = d - 3; if (t < 0 || t >= SEQ_) return;
    const float* hin = (t & 1) ? h1B : h1A;
    float* hout = (t & 1) ? h1A : h1B;
    step_block(sb, rowb, rt, cg, tid, gi1 + (size_t)(t & 1) * 393216,
               hin, hout, nullptr, Whh, bhh, 1, ip);
  }
}

// ---------------- decoder GRU (ungrouped, 2 dispatches) ----------------
template <int D1>
__global__ __launch_bounds__(256) void k_gru(
    const float* __restrict__ x, const float* __restrict__ hin,
    float* __restrict__ hout,
    const float* __restrict__ Wih, const float* __restrict__ Whh,
    const float* __restrict__ bih, const float* __restrict__ bhh) {
  __shared__ float xs[16][(D1 == 2) ? 2 : H_];
  __shared__ float hs[16][H_];
  int bx = blockIdx.x, by = blockIdx.y;
  int start = bx * 16;
  int tid = threadIdx.x;
  for (int idx = tid; idx < 16 * H_; idx += 256) {
    int r = idx >> 8, k = idx & 255;
    int b = start + r;
    hs[r][k] = hin[b * H_ + k];
    if (D1 == H_) xs[r][k] = x[b * H_ + k];
    else if (k < D1) xs[r][k] = x[b * D1 + k];
  }
  __syncthreads();
  int j = tid & 31, rs = tid >> 5;
  int hc = by * 32 + j;
  int cr = hc, cz = H_ + hc, cn = 2 * H_ + hc;
  double ra0 = 0, ra1 = 0, za0 = 0, za1 = 0, ni0 = 0, ni1 = 0, nh0 = 0, nh1 = 0;
  for (int k = 0; k < H_; k++) {
    float wrh = Whh[k * TG_ + cr], wzh = Whh[k * TG_ + cz], wnh = Whh[k * TG_ + cn];
    float h0v = hs[rs][k], h1v = hs[rs + 8][k];
    ra0 += (double)h0v * wrh; ra1 += (double)h1v * wrh;
    za0 += (double)h0v * wzh; za1 += (double)h1v * wzh;
    nh0 += (double)h0v * wnh; nh1 += (double)h1v * wnh;
    if (D1 == H_) {
      float wri = Wih[k * TG_ + cr], wzi = Wih[k * TG_ + cz], wni = Wih[k * TG_ + cn];
      float x0v = xs[rs][k], x1v = xs[rs + 8][k];
      ra0 += (double)x0v * wri; ra1 += (double)x1v * wri;
      za0 += (double)x0v * wzi; za1 += (double)x1v * wzi;
      ni0 += (double)x0v * wni; ni1 += (double)x1v * wni;
    }
  }
  if (D1 != H_) {
    for (int k = 0; k < D1; k++) {
      float wri = Wih[k * TG_ + cr], wzi = Wih[k * TG_ + cz], wni = Wih[k * TG_ + cn];
      float x0v = xs[rs][k], x1v = xs[rs + 8][k];
      ra0 += (double)x0v * wri; ra1 += (double)x1v * wri;
      za0 += (double)x0v * wzi; za1 += (double)x1v * wzi;
      ni0 += (double)x0v * wni; ni1 += (double)x1v * wni;
    }
  }
  double br_i = (double)bih[cr], bz_i = (double)bih[cz], bn_i = (double)bih[cn];
  double br_h = (double)bhh[cr], bz_h = (double)bhh[cz], bn_h = (double)bhh[cn];
  for (int p = 0; p < 2; p++) {
    int r = rs + 8 * p;
    double ra = p ? ra1 : ra0, za = p ? za1 : za0, ni = p ? ni1 : ni0, nh = p ? nh1 : nh0;
    double rr = 1.0 / (1.0 + exp(-(ra + br_i + br_h)));
    double zz = 1.0 / (1.0 + exp(-(za + bz_i + bz_h)));
    double nn = tanh((ni + bn_i) + rr * (nh + bn_h));
    double hv = (double)hs[r][hc];
    float hnew = (float)((1.0 - zz) * nn + zz * hv);
    hout[(start + r) * H_ + hc] = hnew;
  }
}

// ---------------- heads ----------------
__global__ __launch_bounds__(256) void k_heads(const float* __restrict__ lh,
    const float* __restrict__ hgW1, const float* __restrict__ hgb1,
    const float* __restrict__ hgW2, const float* __restrict__ hgb2,
    const float* __restrict__ hgW3, const float* __restrict__ hgb3,
    const float* __restrict__ ceW1, const float* __restrict__ ceb1,
    const float* __restrict__ ceW2, const float* __restrict__ ceb2,
    float* __restrict__ out) {
  __shared__ float hsm[16][H_];
  __shared__ float t1[16][H_];
  __shared__ float t2[16][H2_];
  __shared__ float c2s[16][T_];
  int row0 = blockIdx.x * 16;
  int tid = threadIdx.x;
  for (int idx = tid; idx < 16 * H_; idx += 256) {
    int r = idx >> 8, k = idx & 255;
    hsm[r][k] = lh[(size_t)(row0 + r) * H_ + k];
  }
  __syncthreads();
  {
    int j = tid;
    for (int r = 0; r < 16; r++) {
      double a = 0;
      for (int k = 0; k < H_; k++) a += (double)hsm[r][k] * (double)hgW1[k * H_ + j];
      t1[r][j] = fmaxf((float)(a + (double)hgb1[j]), 0.0f);
    }
  }
  __syncthreads();
  if (tid < H2_) {
    int j = tid;
    for (int r = 0; r < 16; r++) {
      double a = 0;
      for (int k = 0; k < H_; k++) a += (double)t1[r][k] * (double)hgW2[k * H2_ + j];
      t2[r][j] = fmaxf((float)(a + (double)hgb2[j]), 0.0f);
    }
  }
  __syncthreads();
  if (tid < 2 * T_) {
    int j = tid;
    for (int r = 0; r < 16; r++) {
      double a = 0;
      for (int k = 0; k < H2_; k++) a += (double)t2[r][k] * (double)hgW3[k * (2 * T_) + j];
      float v = (float)(a + (double)hgb3[j]);
      int b = row0 + r;
      int t = j >> 1, c = j & 1;
      out[(((size_t)b * S_ + 0) * T_ + t) * 2 + c] = v;
    }
  }
  __syncthreads();
  if (tid < H2_) {
    int j = tid;
    for (int r = 0; r < 16; r++) {
      double a = 0;
      for (int k = 0; k < H_; k++) a += (double)hsm[r][k] * (double)ceW1[k * H2_ + j];
      t2[r][j] = fmaxf((float)(a + (double)ceb1[j]), 0.0f);
    }
  }
  __syncthreads();
  if (tid < T_) {
    int j = tid;
    for (int r = 0; r < 16; r++) {
      double a = 0;
      for (int k = 0; k < H2_; k++) a += (double)t2[r][k] * (double)ceW2[k * T_ + j];
      c2s[r][j] = (float)(a + (double)ceb2[j]);
    }
  }
  __syncthreads();
  if (tid < 16) {
    int r = tid;
    int b = row0 + r;
    double s = 0;
    for (int j = 0; j < T_; j++) s += (double)c2s[r][j];
    float m = (float)(s / 60.0);
    for (int sd = 0; sd < S_; sd++) {
      float d = (float)pow((double)0.9f, (double)sd);
      out[368640 + b * S_ + sd] = __fmul_rn(m, d);
    }
  }
}

// ---------------- hp layer1 ----------------
__global__ __launch_bounds__(256) void k_hp1(const float* __restrict__ lh,
    const float* __restrict__ W1, const float* __restrict__ b1,
    float* __restrict__ h1buf, uint32_t nk0, uint32_t nk1) {
  __shared__ float th[16][H_];
  int row0 = blockIdx.x * 16;
  int tid = threadIdx.x;
  const float SQRT2F = 1.4142135623730951f;
  const float LO = -0x1.fffffep-1f;
  for (int idx = tid; idx < 16 * H_; idx += 256) {
    int r = idx >> 8, k = idx & 255;
    int g = row0 + r;
    int t = g / B_, b = g % B_;
    uint32_t i = ((uint32_t)t * B_ + (uint32_t)b) * H_ + (uint32_t)k;
    uint32_t bits = jax_bits(nk0, nk1, i, NOISE_N);
    float f = bits_to_f01(bits);
    float u = fmaxf(LO, __fadd_rn(__fmul_rn(f, 2.0f), LO));
    float nz = __fmul_rn(SQRT2F, erfinv_f(u));
    float sc = __fdiv_rn(__fmul_rn(0.1f, (float)t), 60.0f);
    th[r][k] = __fadd_rn(lh[(size_t)b * H_ + k], __fmul_rn(nz, sc));
  }
  __syncthreads();
  int j = tid;
  double acc[16];
  for (int r = 0; r < 16; r++) acc[r] = 0.0;
  for (int k = 0; k < H_; k++) {
    double w = (double)W1[k * H_ + j];
    for (int r = 0; r < 16; r++) acc[r] += (double)th[r][k] * w;
  }
  double bb = (double)b1[j];
  for (int r = 0; r < 16; r++)
    h1buf[(size_t)(row0 + r) * H_ + j] = fmaxf((float)(acc[r] + bb), 0.0f);
}

// ---------------- hp layer2 + gumbel + argmax (f32, validated r2) ----------------
__global__ __launch_bounds__(256) void k_hp2(const float* __restrict__ h1buf,
    const float* __restrict__ W2, const float* __restrict__ b2,
    unsigned long long* __restrict__ samples, uint32_t sk0, uint32_t sk1) {
  __shared__ float h1[16][H_];
  int row0 = blockIdx.x * 16;
  int cat0 = blockIdx.y * 128;
  int tid = threadIdx.x;
  for (int idx = tid; idx < 16 * H_ / 4; idx += 256) {
    int r = idx >> 6, k4 = (idx & 63) << 2;
    *(float4*)&h1[r][k4] = *(const float4*)&h1buf[(size_t)(row0 + r) * H_ + k4];
  }
  __syncthreads();
  int wave = tid >> 6;
  int lane = tid & 63;
  int catA = cat0 + 2 * lane;
  int rbase = 4 * wave;

  float acc[4][2];
  for (int q = 0; q < 4; q++) { acc[q][0] = 0.0f; acc[q][1] = 0.0f; }
  const float* w2p = W2 + catA;
  for (int k = 0; k < H_; k += 4) {
    float4 hv0 = *(const float4*)&h1[rbase + 0][k];
    float4 hv1 = *(const float4*)&h1[rbase + 1][k];
    float4 hv2 = *(const float4*)&h1[rbase + 2][k];
    float4 hv3 = *(const float4*)&h1[rbase + 3][k];
#pragma unroll
    for (int kk = 0; kk < 4; kk++) {
      float2 w = *(const float2*)&w2p[(size_t)(k + kk) * CAT_];
      float h0 = (&hv0.x)[kk], h1v = (&hv1.x)[kk], h2 = (&hv2.x)[kk], h3 = (&hv3.x)[kk];
      acc[0][0] = __fmaf_rn(h0, w.x, acc[0][0]); acc[0][1] = __fmaf_rn(h0, w.y, acc[0][1]);
      acc[1][0] = __fmaf_rn(h1v, w.x, acc[1][0]); acc[1][1] = __fmaf_rn(h1v, w.y, acc[1][1]);
      acc[2][0] = __fmaf_rn(h2, w.x, acc[2][0]); acc[2][1] = __fmaf_rn(h2, w.y, acc[2][1]);
      acc[3][0] = __fmaf_rn(h3, w.x, acc[3][0]); acc[3][1] = __fmaf_rn(h3, w.y, acc[3][1]);
    }
  }
  float lg[4][2];
  float b0 = b2[catA], b1v = b2[catA + 1];
  for (int q = 0; q < 4; q++) {
    lg[q][0] = __fadd_rn(acc[q][0], b0);
    lg[q][1] = __fadd_rn(acc[q][1], b1v);
  }

  int t = row0 / B_;
  int bbase = row0 % B_;
#pragma unroll
  for (int s = 0; s < S_ - 1; s++) {
#pragma unroll
    for (int q = 0; q < 4; q++) {
      int brow = bbase + rbase + q;
      uint32_t ibase = (((uint32_t)s * T_ + (uint32_t)t) * B_ + (uint32_t)brow) * CAT_ + (uint32_t)catA;
      float g0 = gumbel_f32(jax_bits(sk0, sk1, ibase, GUMBEL_N));
      float g1 = gumbel_f32(jax_bits(sk0, sk1, ibase + 1u, GUMBEL_N));
      float s0 = __fadd_rn(g0, lg[q][0]);
      float s1 = __fadd_rn(g1, lg[q][1]);
      uint32_t k0 = orderkey(s0), k1 = orderkey(s1);
      uint32_t bestk; int bestc;
      if (k1 > k0) { bestk = k1; bestc = catA + 1; }
      else         { bestk = k0; bestc = catA; }
      uint32_t m = bestk;
      for (int off = 1; off < 64; off <<= 1) {
        uint32_t o = __shfl_xor(m, off, 64);
        m = m > o ? m : o;
      }
      unsigned long long mask = __ballot(bestk == m);
      int src = __ffsll(mask) - 1;
      int wcat = __shfl(bestc, src, 64);
      if (lane == 0) {
        unsigned long long p =
            (((unsigned long long)m) << 32) | (unsigned long long)(~(uint32_t)wcat);
        atomicMax(&samples[((size_t)s * T_ + t) * B_ + brow], p);
      }
    }
  }
}

// ---------------- decode samples -> grid points ----------------
__global__ void k_emit(const unsigned long long* __restrict__ samples, float* __restrict__ out) {
  int gid = blockIdx.x * blockDim.x + threadIdx.x;
  if (gid >= (S_ - 1) * T_ * B_) return;
  int b = gid % B_;
  int t = (gid / B_) % T_;
  int s = gid / (B_ * T_);
  unsigned long long v = samples[gid];
  uint32_t cat = ~(uint32_t)(v & 0xFFFFFFFFu);
  float xi = (float)(cat & 63u);
  float yi = (float)(cat >> 6);
  float px = -50.0f + xi * 1.5625f + 0.78125f;
  float py = -50.0f + yi * 1.5625f + 0.78125f;
  size_t o = (((size_t)b * S_ + (size_t)(s + 1)) * T_ + t) * 2;
  out[o] = px;
  out[o + 1] = py;
}

// ---------------- host ----------------
extern "C" void kernel_launch(void* const* d_in, const int* in_sizes, int n_in,
                              void* d_out, int out_size, void* d_ws, size_t ws_size,
                              hipStream_t stream) {
  (void)in_sizes; (void)n_in; (void)out_size; (void)ws_size;
  const float* hist   = (const float*)d_in[0];
  const float* emb    = (const float*)d_in[1];
  const float* feW1   = (const float*)d_in[2];
  const float* feb1   = (const float*)d_in[3];
  const float* feW2   = (const float*)d_in[4];
  const float* feb2   = (const float*)d_in[5];
  const float* encWih = (const float*)d_in[6];
  const float* encWhh = (const float*)d_in[7];
  const float* encbih = (const float*)d_in[8];
  const float* encbhh = (const float*)d_in[9];
  const float* dWih0  = (const float*)d_in[10];
  const float* dWhh0  = (const float*)d_in[11];
  const float* dbih0  = (const float*)d_in[12];
  const float* dbhh0  = (const float*)d_in[13];
  const float* dWih1  = (const float*)d_in[14];
  const float* dWhh1  = (const float*)d_in[15];
  const float* dbih1  = (const float*)d_in[16];
  const float* dbhh1  = (const float*)d_in[17];
  const float* hgW1   = (const float*)d_in[18];
  const float* hgb1   = (const float*)d_in[19];
  const float* hgW2   = (const float*)d_in[20];
  const float* hgb2   = (const float*)d_in[21];
  const float* hgW3   = (const float*)d_in[22];
  const float* hgb3   = (const float*)d_in[23];
  const float* ceW1   = (const float*)d_in[24];
  const float* ceb1   = (const float*)d_in[25];
  const float* ceW2   = (const float*)d_in[26];
  const float* ceb2   = (const float*)d_in[27];
  const float* hpW1   = (const float*)d_in[28];
  const float* hpb1   = (const float*)d_in[29];
  const float* hpW2   = (const float*)d_in[30];
  const float* hpb2   = (const float*)d_in[31];
  float* out = (float*)d_out;
  float* ws = (float*)d_ws;

  // workspace layout (float offsets)
  float* feat  = ws;                        // 6,553,600 [t][b][h]
  float* ys0   = ws + 6553600;              // 6,553,600 [t][b][h]
  float* gi0   = ws + 13107200;             // 2 x 512 x 768
  float* gi1   = ws + 13893632;             // 2 x 512 x 768
  float* h0A   = ws + 14680064;
  float* h0B   = h0A + 131072;
  float* h1A   = h0B + 131072;
  float* h1B   = h1A + 131072;
  float* dech0 = h1B + 131072;
  float* lh    = dech0 + 131072;
  float* x0buf = lh + 131072;               // 1024
  int*   ip    = (int*)(x0buf + 1024);      // 2048 ints reserved
  unsigned long long* samples =
      (unsigned long long*)(((uintptr_t)(ip + 2048) + 255) & ~(uintptr_t)255);
  float* h1hp  = ws;                        // alias: feat+ys0 head, dead after encoder

  uint32_t kn0, kn1, ks0, ks1;
#if JAX_PARTITIONABLE
  tf2x32(0u, 42u, 0u, 0u, kn0, kn1);
  tf2x32(0u, 42u, 0u, 1u, ks0, ks1);
#else
  { uint32_t a0, a1, b0, b1;
    tf2x32(0u, 42u, 0u, 2u, a0, a1);
    tf2x32(0u, 42u, 1u, 3u, b0, b1);
    kn0 = a0; kn1 = b0; ks0 = a1; ks1 = b1; }
#endif

  k_init<<<dim3(1), dim3(512), 0, stream>>>(hist, x0buf, ip);
  k_zero<<<dim3((524288 + 255) / 256), dim3(256), 0, stream>>>((uint32_t*)h0A, 524288);
  k_zero<<<dim3((307200 + 255) / 256), dim3(256), 0, stream>>>((uint32_t*)samples, 307200);
  k_feat<<<dim3(1600), dim3(256), 0, stream>>>(hist, emb, feW1, feb1, feW2, feb2, ip, feat);

  // pipelined encoder: 53 dispatches, 4 groups x 288 blocks each
  for (int d = 0; d < SEQ_ + 3; d++) {
    k_pipe<<<dim3(1152), dim3(256), 0, stream>>>(d,
        feat, ys0, gi0, gi1, h0A, h0B, h1A, h1B,
        encWih, encWhh, encbih, encbhh, ip);
  }
  // final hiddens: layer0 in h0A, layer1 in h1A (t=49 odd -> writes slot A)

  k_gru<2><<<dim3(32, 8), dim3(256), 0, stream>>>(
      x0buf, h0A, dech0, dWih0, dWhh0, dbih0, dbhh0);
  k_gru<H_><<<dim3(32, 8), dim3(256), 0, stream>>>(
      dech0, h1A, lh, dWih1, dWhh1, dbih1, dbhh1);

  k_heads<<<dim3(32), dim3(256), 0, stream>>>(lh, hgW1, hgb1, hgW2, hgb2, hgW3, hgb3,
                                              ceW1, ceb1, ceW2, ceb2, out);
  k_hp1<<<dim3(1920), dim3(256), 0, stream>>>(lh, hpW1, hpb1, h1hp, kn0, kn1);
  k_hp2<<<dim3(1920, 32), dim3(256), 0, stream>>>(h1hp, hpW2, hpb2, samples, ks0, ks1);
  k_emit<<<dim3(600), dim3(256), 0, stream>>>(samples, out);
}